// Round 4
// baseline (1611.501 us; speedup 1.0000x reference)
//
#include <hip/hip_runtime.h>
#include <hip/hip_bf16.h>
#include <math.h>

#define N_COLS 2048   // N
#define N_ROWS 128    // n
#define KW     32     // W columns (m=30 + p=2)
#define WST    36     // LDS row stride for W (floats; lane stride 144B -> benign)
#define PST    20     // LDS row stride for panel (floats; 16B-aligned rows)

// ---------------- transpose kernels (gather efficiency, used only if ws fits) ----------------
__global__ void transpose_y_kernel(const float* __restrict__ Y, float* __restrict__ Yt) {
  __shared__ float tile[32][33];
  const int bx = blockIdx.x, by = blockIdx.y;
  const int tx = threadIdx.x, ty = threadIdx.y;
#pragma unroll
  for (int q = 0; q < 4; ++q)
    tile[ty + 8 * q][tx] = Y[(by * 32 + ty + 8 * q) * N_COLS + bx * 32 + tx];
  __syncthreads();
#pragma unroll
  for (int q = 0; q < 4; ++q)
    Yt[(bx * 32 + ty + 8 * q) * N_ROWS + by * 32 + tx] = tile[tx][ty + 8 * q];
}

__global__ void transpose_x_kernel(const float2* __restrict__ X, float2* __restrict__ Xt) {
  __shared__ float2 tile[32][33];
  const int bx = blockIdx.x, by = blockIdx.y;
  const int tx = threadIdx.x, ty = threadIdx.y;
#pragma unroll
  for (int q = 0; q < 4; ++q)
    tile[ty + 8 * q][tx] = X[(by * 32 + ty + 8 * q) * N_COLS + bx * 32 + tx];
  __syncthreads();
#pragma unroll
  for (int q = 0; q < 4; ++q)
    Xt[(bx * 32 + ty + 8 * q) * N_ROWS + by * 32 + tx] = tile[tx][ty + 8 * q];
}

// ---------------- panel factorization: one wave, registers + __shfl broadcast ----------------
// Panel = 16 cols (global 16p..16p+15) x 128 rows in P (row-major, stride PST), y implicit col.
// LDL raw columns: step k: inv=1/P[k][k]; for j>k: P[i][j] -= P[i][k]*inv*P[k][j] (i>k).
// Lane l owns rows l and l+64. Pivot row broadcast per-element via __shfl.
static __device__ __forceinline__ void factor_panel(
    const int p, const int l, float* __restrict__ P, float* __restrict__ yL,
    float* __restrict__ invd, float& ld, float& yb) {
  float pr0[16], pr1[16];
#pragma unroll
  for (int q = 0; q < 4; ++q) {
    const float4 v0 = *(const float4*)&P[l * PST + 4 * q];
    const float4 v1 = *(const float4*)&P[(l + 64) * PST + 4 * q];
    pr0[4 * q + 0] = v0.x; pr0[4 * q + 1] = v0.y; pr0[4 * q + 2] = v0.z; pr0[4 * q + 3] = v0.w;
    pr1[4 * q + 0] = v1.x; pr1[4 * q + 1] = v1.y; pr1[4 * q + 2] = v1.z; pr1[4 * q + 3] = v1.w;
  }
  float py0 = yL[l], py1 = yL[l + 64];
  const int pbase = p << 4;
#pragma unroll
  for (int k = 0; k < 16; ++k) {
    const int prow = pbase + k;
    const int olane = prow & 63;
    const bool hi = prow >= 64;      // compile-time after p,k unroll
    const float dk = __shfl(hi ? pr1[k] : pr0[k], olane, 64);
    const float yk = __shfl(hi ? py1 : py0, olane, 64);
    const float inv = __builtin_amdgcn_rcpf(dk);
    if (l == 0) { ld += 0.5f * __logf(dk); yb += yk * yk * inv; invd[k] = inv; }
    const float f0 = (l > prow) ? pr0[k] * inv : 0.0f;
    const float f1 = (l + 64 > prow) ? pr1[k] * inv : 0.0f;
#pragma unroll
    for (int j = k + 1; j < 16; ++j) {
      const float rk = __shfl(hi ? pr1[j] : pr0[j], olane, 64);
      pr0[j] = fmaf(-f0, rk, pr0[j]);
      pr1[j] = fmaf(-f1, rk, pr1[j]);
    }
    py0 = fmaf(-f0, yk, py0);
    py1 = fmaf(-f1, yk, py1);
  }
#pragma unroll
  for (int q = 0; q < 4; ++q) {
    *(float4*)&P[l * PST + 4 * q] =
        make_float4(pr0[4 * q + 0], pr0[4 * q + 1], pr0[4 * q + 2], pr0[4 * q + 3]);
    *(float4*)&P[(l + 64) * PST + 4 * q] =
        make_float4(pr1[4 * q + 0], pr1[4 * q + 1], pr1[4 * q + 2], pr1[4 * q + 3]);
  }
  yL[l] = py0;
  yL[l + 64] = py1;
}

// ---------------- main kernel: one block per b ----------------
__global__ __launch_bounds__(256, 3) void chol_main(
    const float* __restrict__ Y, const float* __restrict__ X,
    const float* __restrict__ theta, const int* __restrict__ NNmax,
    const int* __restrict__ mPtr, const float* __restrict__ Yt,
    const float* __restrict__ Xt, const int useT, const int mMax,
    float* __restrict__ out) {
  // union: Wl (128x36 = 4608 f) overlaps the two panel buffers (2x 128x20 = 5120 f)
  __shared__ __align__(16) float uMem[5120];
  __shared__ float yL[N_ROWS];
  __shared__ float swL[N_ROWS];
  __shared__ __align__(16) float invd[16];
  __shared__ float smaskL[KW];
  __shared__ int nnL[KW];
  __shared__ int nzflag;
  float* const Wl = uMem;
  float* const P0 = uMem;
  float* const P1 = uMem + 2560;

  const int b = blockIdx.x;
  const int t = threadIdx.x;
  const int ti = t & 15;
  const int tj = t >> 4;

  // ---- per-block scalars ----
  const float th0 = theta[0], th1 = theta[1], th2 = theta[2], th3 = theta[3], th4 = theta[4];
  const float th5 = theta[5], th6 = theta[6], th7 = theta[7], th8 = theta[8], th9 = theta[9];
  const float logs = -__logf((float)(b + 1));
  const float nug = fmaxf(__expf(th0 + th1 * logs) - 1e-5f, 0.0f) + 1e-5f;
  const float sigma = __expf(th3 + th4 * logs);
  const float sig2 = sigma * sigma;
  const float invNug = 1.0f / nug;
  const float invL2 = __expf(-2.0f * th5) * (1.0f / 3.0f);
  const float sx0 = __expf(th6 + th8 * logs);
  const float sx1 = __expf(th7 + th9 * logs);
  int m = *mPtr; if (m > 30) m = 30;

  if (t == 0) nzflag = 0;
  if (t < KW) {
    nnL[t] = (t < m) ? NNmax[b * mMax + t] : 0;
    smaskL[t] = (t < m && t < b) ? __expf(0.5f * (float)(t + 1) * th2) : 0.0f;
  }
  __syncthreads();

  // ---- fill W (128 x 32) in LDS ----
  {
    const int i0 = t & 127;
    const int jb = t >> 7;
#pragma unroll
    for (int q = 0; q < 16; ++q) {
      const int j = jb + 2 * q;
      float v;
      if (j < m) {
        v = (useT ? Yt[nnL[j] * N_ROWS + i0] : Y[i0 * N_COLS + nnL[j]]) * smaskL[j];
      } else if (j < m + 2) {
        const int kc = j - m;
        v = useT ? Xt[(b * N_ROWS + i0) * 2 + kc] : X[(i0 * N_COLS + b) * 2 + kc];
        v *= (kc == 0) ? sx0 : sx1;
      } else {
        v = 0.0f;
      }
      Wl[i0 * WST + j] = v;
    }
  }
  if (t < N_ROWS) {
    const float2 xv = useT ? ((const float2*)Xt)[b * N_ROWS + t]
                           : ((const float2*)X)[t * N_COLS + b];
    if (xv.x != 0.0f || xv.y != 0.0f) atomicOr(&nzflag, 1);
    yL[t] = useT ? Yt[b * N_ROWS + t] : Y[t * N_COLS + b];
  }
  __syncthreads();
  if (nzflag == 0 && t < N_ROWS) {  // xz: zero the X part of W
    Wl[t * WST + m] = 0.0f;
    Wl[t * WST + m + 1] = 0.0f;
  }
  __syncthreads();

  // ---- Gram: gr[a][c] = W[i,:].W[j,:]  (i=ti+16a, j=tj+16c); c tiled by 4 for regs ----
  float gr[8][8];
#pragma unroll
  for (int a = 0; a < 8; ++a)
#pragma unroll
    for (int c = 0; c < 8; ++c) gr[a][c] = 0.0f;

#pragma unroll
  for (int g = 0; g < 2; ++g) {
#pragma unroll
    for (int kk = 0; kk < KW; kk += 4) {
      float4 wc[4];
#pragma unroll
      for (int c = 0; c < 4; ++c)
        wc[c] = *(const float4*)&Wl[(tj + 16 * (4 * g + c)) * WST + kk];
#pragma unroll
      for (int a = 0; a < 8; ++a) {
        const float4 wa = *(const float4*)&Wl[(ti + 16 * a) * WST + kk];
#pragma unroll
        for (int c = 0; c < 4; ++c) {
          float acc = gr[a][4 * g + c];
          acc = fmaf(wa.x, wc[c].x, acc);
          acc = fmaf(wa.y, wc[c].y, acc);
          acc = fmaf(wa.z, wc[c].z, acc);
          acc = fmaf(wa.w, wc[c].w, acc);
          gr[a][4 * g + c] = acc;
        }
      }
    }
  }

  // diag (row sum-of-squares) to LDS
  if (ti == tj) {
#pragma unroll
    for (int a = 0; a < 8; ++a) swL[ti + 16 * a] = gr[a][a];
  }
  __syncthreads();   // Wl reads done; panel buffers may be written after this

  // ---- transform dot -> G = I + (dot + matern*sig2)/nug ----
  if (b != 0) {
    float swa[8], swc[8];
#pragma unroll
    for (int a = 0; a < 8; ++a) swa[a] = swL[ti + 16 * a];
#pragma unroll
    for (int c = 0; c < 8; ++c) swc[c] = swL[tj + 16 * c];
#pragma unroll
    for (int a = 0; a < 8; ++a)
#pragma unroll
      for (int c = 0; c < 8; ++c) {
        const float d = gr[a][c];
        float r2 = (swa[a] + swc[c] - 2.0f * d) * invL2;
        r2 = fmaxf(r2, 0.0f);
        const float cc = sqrtf(3.0f * r2);
        const float mat = (1.0f + cc) * __expf(-cc);
        float g = fmaf(mat, sig2, d) * invNug;
        if (a == c) g += (ti == tj) ? 1.0f : 0.0f;
        gr[a][c] = g;
      }
  } else {
#pragma unroll
    for (int a = 0; a < 8; ++a)
#pragma unroll
      for (int c = 0; c < 8; ++c) gr[a][c] = (ti == tj && a == c) ? 1.0f : 0.0f;
  }

  // write panel 0 columns into P0 (all rows)
#pragma unroll
  for (int a = 0; a < 8; ++a) P0[(ti + 16 * a) * PST + tj] = gr[a][0];

  // ---- 8 panels: factor (wave 0) + rank-16 trailing update (all threads) ----
  float ld = 0.0f, yb = 0.0f;
#pragma unroll
  for (int p = 0; p < 8; ++p) {
    float* const Pc = (p & 1) ? P1 : P0;
    float* const Pn = (p & 1) ? P0 : P1;
    __syncthreads();                       // panel p columns complete in Pc
    if (t < 64) {
      // Explicit spill of gr[a][4..8) into Pn (dead data: panel p-1, already
      // consumed). Frees 32 VGPRs so factor_panel's pr0/pr1 fit without
      // scratch spill. Pn is only written by the export AFTER the mid
      // barrier, and the reload below happens before it.
#pragma unroll
      for (int a = 0; a < 8; ++a)
        *(float4*)&Pn[t * 36 + 4 * a] = make_float4(gr[a][4], gr[a][5], gr[a][6], gr[a][7]);
      factor_panel(p, t, Pc, yL, invd, ld, yb);
#pragma unroll
      for (int a = 0; a < 8; ++a) {
        const float4 v = *(const float4*)&Pn[t * 36 + 4 * a];
        gr[a][4] = v.x; gr[a][5] = v.y; gr[a][6] = v.z; gr[a][7] = v.w;
      }
    }
    __syncthreads();                       // factored panel + invd + yL visible
    if (p < 7) {
      // trailing update, c tiled in groups of 4 to keep VGPR bounded
#pragma unroll
      for (int g = 0; g < 2; ++g) {
        const int clo = (4 * g > p + 1) ? 4 * g : p + 1;   // compile-time after unroll
        const int chi = 4 * g + 4;
        if (clo < chi) {
#pragma unroll
          for (int kk = 0; kk < 16; kk += 4) {
            const float4 iv4 = *(const float4*)&invd[kk];
            float4 rc4[4];
#pragma unroll
            for (int c = 0; c < 4; ++c)
              if (4 * g + c >= clo)
                rc4[c] = *(const float4*)&Pc[(tj + 16 * (4 * g + c)) * PST + kk];
#pragma unroll
            for (int a = p + 1; a < 8; ++a) {
              float4 ra = *(const float4*)&Pc[(ti + 16 * a) * PST + kk];
              ra.x *= iv4.x; ra.y *= iv4.y; ra.z *= iv4.z; ra.w *= iv4.w;
#pragma unroll
              for (int c = 0; c < 4; ++c) {
                if (4 * g + c >= clo) {
                  float acc = gr[a][4 * g + c];
                  acc = fmaf(-ra.x, rc4[c].x, acc);
                  acc = fmaf(-ra.y, rc4[c].y, acc);
                  acc = fmaf(-ra.z, rc4[c].z, acc);
                  acc = fmaf(-ra.w, rc4[c].w, acc);
                  gr[a][4 * g + c] = acc;
                }
              }
            }
          }
        }
      }
      // export next panel's columns (rows >= 16(p+1) are the only ones read)
#pragma unroll
      for (int a = p + 1; a < 8; ++a) Pn[(ti + 16 * a) * PST + tj] = gr[a][p + 1];
    }
  }

  // ---- final reduction (thread 0 == lane 0 of wave 0, holds ld/yb) ----
  if (t == 0) {
    const float alpha = 2.0625f;          // (1/NUG_MULT^2)+2
    const float alphaPost = alpha + 64.0f;
    const float beta = 1.0625f * nug;     // nug*(alpha-1)
    const float betaPost = beta + 0.5f * yb;
    const float loglik = -ld + alpha * __logf(beta) - alphaPost * __logf(betaPost)
                       + lgammaf(alphaPost) - lgammaf(alpha);
    atomicAdd(out, -loglik);
  }
}

// ---------------- host launch ----------------
extern "C" void kernel_launch(void* const* d_in, const int* in_sizes, int n_in,
                              void* d_out, int out_size, void* d_ws, size_t ws_size,
                              hipStream_t stream) {
  const float* Y = (const float*)d_in[0];
  const float* X = (const float*)d_in[1];
  const float* theta = (const float*)d_in[2];
  const int* NNmax = (const int*)d_in[3];
  const int* mPtr = (const int*)d_in[4];
  float* out = (float*)d_out;
  const int mMax = in_sizes[3] / N_COLS;  // 64

  hipMemsetAsync(out, 0, sizeof(float) * out_size, stream);

  float* Yt = (float*)d_ws;                         // 2048*128 floats
  float* Xt = (float*)d_ws + N_COLS * N_ROWS;       // 2048*128*2 floats
  const size_t need = (size_t)(N_COLS * N_ROWS * 3) * sizeof(float);
  const int useT = (ws_size >= need) ? 1 : 0;

  if (useT) {
    dim3 tb(32, 8);
    transpose_y_kernel<<<dim3(N_COLS / 32, N_ROWS / 32), tb, 0, stream>>>(Y, Yt);
    transpose_x_kernel<<<dim3(N_COLS / 32, N_ROWS / 32), tb, 0, stream>>>(
        (const float2*)X, (float2*)Xt);
  }
  chol_main<<<N_COLS, 256, 0, stream>>>(Y, X, theta, NNmax, mPtr, Yt, Xt, useT, mMax, out);
}

// Round 5
// 1058.577 us; speedup vs baseline: 1.5223x; 1.5223x over previous
//
#include <hip/hip_runtime.h>
#include <math.h>

#define N_COLS 2048   // N
#define N_ROWS 128    // n
#define KW     32     // W columns (m=30 + p=2)
#define WST    36     // LDS row stride for W (floats)
#define PST    20     // LDS row stride for panel (floats; 16B-aligned rows)

// ---------------- panel factorization: one wave, registers + __shfl broadcast ----------------
// Panel = 16 cols (global 16p..16p+15) x 128 rows in P (row stride PST), y implicit col.
// LDL raw columns: step k: inv=1/P[k][k]; for j>k: P[i][j] -= P[i][k]*inv*P[k][j] (i>k).
// Lane l owns rows l and l+64. p is RUNTIME (uniform); k/j loops compile-time.
static __device__ __forceinline__ void factor_panel(
    const int p, const int l, float* __restrict__ P, float* __restrict__ yL,
    float* __restrict__ invd, float& ld, float& yb) {
  float pr0[16], pr1[16];
#pragma unroll
  for (int qd = 0; qd < 4; ++qd) {
    const float4 v0 = *(const float4*)&P[l * PST + 4 * qd];
    const float4 v1 = *(const float4*)&P[(l + 64) * PST + 4 * qd];
    pr0[4 * qd + 0] = v0.x; pr0[4 * qd + 1] = v0.y; pr0[4 * qd + 2] = v0.z; pr0[4 * qd + 3] = v0.w;
    pr1[4 * qd + 0] = v1.x; pr1[4 * qd + 1] = v1.y; pr1[4 * qd + 2] = v1.z; pr1[4 * qd + 3] = v1.w;
  }
  float py0 = yL[l], py1 = yL[l + 64];
  const int pbase = p << 4;
#pragma unroll
  for (int k = 0; k < 16; ++k) {
    const int prow = pbase + k;      // runtime uniform
    const int olane = prow & 63;
    const bool hi = prow >= 64;      // runtime uniform -> cndmask select
    const float dk = __shfl(hi ? pr1[k] : pr0[k], olane, 64);
    const float yk = __shfl(hi ? py1 : py0, olane, 64);
    const float inv = __builtin_amdgcn_rcpf(dk);
    if (l == 0) { ld += 0.5f * __logf(dk); yb += yk * yk * inv; invd[k] = inv; }
    const float f0 = (l > prow) ? pr0[k] * inv : 0.0f;
    const float f1 = (l + 64 > prow) ? pr1[k] * inv : 0.0f;
#pragma unroll
    for (int j = k + 1; j < 16; ++j) {
      const float rk = __shfl(hi ? pr1[j] : pr0[j], olane, 64);
      pr0[j] = fmaf(-f0, rk, pr0[j]);
      pr1[j] = fmaf(-f1, rk, pr1[j]);
    }
    py0 = fmaf(-f0, yk, py0);
    py1 = fmaf(-f1, yk, py1);
  }
#pragma unroll
  for (int qd = 0; qd < 4; ++qd) {
    *(float4*)&P[l * PST + 4 * qd] =
        make_float4(pr0[4 * qd + 0], pr0[4 * qd + 1], pr0[4 * qd + 2], pr0[4 * qd + 3]);
    *(float4*)&P[(l + 64) * PST + 4 * qd] =
        make_float4(pr1[4 * qd + 0], pr1[4 * qd + 1], pr1[4 * qd + 2], pr1[4 * qd + 3]);
  }
  yL[l] = py0;
  yL[l + 64] = py1;
}

// ---------------- main kernel: one block (512 threads) per b ----------------
// Thread (ti,tj), ti=t&15, tj=t>>4 (0..31) owns G[ti+16a][tj+32c], a<8, c<4 -> acc[8][4].
__global__ __launch_bounds__(512, 4) void chol_main(
    const float* __restrict__ Y, const float* __restrict__ X,
    const float* __restrict__ theta, const int* __restrict__ NNmax,
    const int* __restrict__ mPtr, const int mMax, float* __restrict__ out) {
  // union: Wl (128x36 = 4608 f) overlaps the two panel buffers (2x 128x20 = 5120 f)
  __shared__ __align__(16) float uMem[5120];
  __shared__ float yL[N_ROWS];
  __shared__ float swL[N_ROWS];
  __shared__ __align__(16) float invd[16];
  __shared__ float smaskL[KW];
  __shared__ int nnL[KW];
  __shared__ int nzflag;
  float* const Wl = uMem;
  float* const P0 = uMem;
  float* const P1 = uMem + 2560;

  const int b = blockIdx.x;
  const int t = threadIdx.x;
  const int ti = t & 15;
  const int tj = t >> 4;   // 0..31

  // ---- per-block scalars (redundant per thread) ----
  const float th0 = theta[0], th1 = theta[1], th2 = theta[2], th3 = theta[3], th4 = theta[4];
  const float th5 = theta[5], th6 = theta[6], th7 = theta[7], th8 = theta[8], th9 = theta[9];
  const float logs = -__logf((float)(b + 1));
  const float nug = fmaxf(__expf(th0 + th1 * logs) - 1e-5f, 0.0f) + 1e-5f;
  const float sigma = __expf(th3 + th4 * logs);
  const float sig2 = sigma * sigma;
  const float invNug = 1.0f / nug;
  const float invL2 = __expf(-2.0f * th5) * (1.0f / 3.0f);
  const float sx0 = __expf(th6 + th8 * logs);
  const float sx1 = __expf(th7 + th9 * logs);
  int m = *mPtr; if (m > 30) m = 30;

  if (t == 0) nzflag = 0;
  if (t < KW) {
    nnL[t] = (t < m) ? NNmax[b * mMax + t] : 0;
    smaskL[t] = (t < m && t < b) ? __expf(0.5f * (float)(t + 1) * th2) : 0.0f;
  }
  __syncthreads();

  // ---- fill W (128 x 32) in LDS: each thread fills 8 cols of one row ----
  {
    const int i0 = t & 127;
    const int jb = t >> 7;   // 0..3
#pragma unroll
    for (int qq = 0; qq < 8; ++qq) {
      const int j = jb + 4 * qq;
      float v;
      if (j < m) {
        v = Y[i0 * N_COLS + nnL[j]] * smaskL[j];
      } else if (j < m + 2) {
        const int kc = j - m;
        v = X[(i0 * N_COLS + b) * 2 + kc] * ((kc == 0) ? sx0 : sx1);
      } else {
        v = 0.0f;
      }
      Wl[i0 * WST + j] = v;
    }
  }
  if (t < N_ROWS) {
    const float2 xv = ((const float2*)X)[t * N_COLS + b];
    if (xv.x != 0.0f || xv.y != 0.0f) atomicOr(&nzflag, 1);
    yL[t] = Y[t * N_COLS + b];
  }
  __syncthreads();
  if (nzflag == 0 && t < N_ROWS) {  // xz: zero the X part of W
    Wl[t * WST + m] = 0.0f;
    Wl[t * WST + m + 1] = 0.0f;
  }
  __syncthreads();

  // ---- Gram: acc[a][c] = W[i,:].W[j,:], i=ti+16a, j=tj+32c ----
  float acc[8][4];
#pragma unroll
  for (int a = 0; a < 8; ++a)
#pragma unroll
    for (int c = 0; c < 4; ++c) acc[a][c] = 0.0f;

#pragma unroll
  for (int kk = 0; kk < KW; kk += 4) {
    float4 wc[4];
#pragma unroll
    for (int c = 0; c < 4; ++c)
      wc[c] = *(const float4*)&Wl[(tj + 32 * c) * WST + kk];
#pragma unroll
    for (int a = 0; a < 8; ++a) {
      const float4 wa = *(const float4*)&Wl[(ti + 16 * a) * WST + kk];
#pragma unroll
      for (int c = 0; c < 4; ++c) {
        float v = acc[a][c];
        v = fmaf(wa.x, wc[c].x, v);
        v = fmaf(wa.y, wc[c].y, v);
        v = fmaf(wa.z, wc[c].z, v);
        v = fmaf(wa.w, wc[c].w, v);
        acc[a][c] = v;
      }
    }
  }

  // diag (row sum-of-squares) to swL: i==j needs ti==(tj&15); a = 2c + (tj>>4)
  if (ti == (tj & 15)) {
    if (tj < 16) {
#pragma unroll
      for (int c = 0; c < 4; ++c) swL[tj + 32 * c] = acc[2 * c][c];
    } else {
#pragma unroll
      for (int c = 0; c < 4; ++c) swL[tj + 32 * c] = acc[2 * c + 1][c];
    }
  }
  __syncthreads();

  // ---- transform dot -> G = I + (dot + matern*sig2)/nug ----
  if (b != 0) {
    float swa[8], swc[4];
#pragma unroll
    for (int a = 0; a < 8; ++a) swa[a] = swL[ti + 16 * a];
#pragma unroll
    for (int c = 0; c < 4; ++c) swc[c] = swL[tj + 32 * c];
#pragma unroll
    for (int a = 0; a < 8; ++a)
#pragma unroll
      for (int c = 0; c < 4; ++c) {
        const float d = acc[a][c];
        float r2 = (swa[a] + swc[c] - 2.0f * d) * invL2;
        r2 = fmaxf(r2, 0.0f);
        const float cc = sqrtf(3.0f * r2);
        const float mat = (1.0f + cc) * __expf(-cc);
        float g = fmaf(mat, sig2, d) * invNug;
        if (ti + 16 * a == tj + 32 * c) g += 1.0f;
        acc[a][c] = g;
      }
  } else {
#pragma unroll
    for (int a = 0; a < 8; ++a)
#pragma unroll
      for (int c = 0; c < 4; ++c)
        acc[a][c] = (ti + 16 * a == tj + 32 * c) ? 1.0f : 0.0f;
  }

  // export panel 0 (cols 0..15, all 128 rows): owned by threads tj<16, c=0
  if (tj < 16) {
#pragma unroll
    for (int a = 0; a < 8; ++a) P0[(ti + 16 * a) * PST + tj] = acc[a][0];
  }

  // ---- 8 panels (runtime loop): factor (wave 0) + rank-16 trailing update ----
  float ld = 0.0f, yb = 0.0f;
  for (int p = 0; p < 8; ++p) {
    float* const Pc = (p & 1) ? P1 : P0;
    float* const Pn = (p & 1) ? P0 : P1;
    __syncthreads();                       // panel p columns complete in Pc
    if (t < 64) factor_panel(p, t, Pc, yL, invd, ld, yb);
    __syncthreads();                       // factored panel + invd + yL visible
    const int q = p + 1;
    if (q < 8) {
      const int b16q = 16 * q;
#pragma unroll
      for (int kk = 0; kk < 16; kk += 4) {
        const float4 iv4 = *(const float4*)&invd[kk];
        float4 rc4[4];
#pragma unroll
        for (int c = 0; c < 4; ++c)
          if (32 * c + 31 >= b16q)          // uniform; dead c-groups skipped
            rc4[c] = *(const float4*)&Pc[(tj + 32 * c) * PST + kk];
#pragma unroll
        for (int a = 0; a < 8; ++a) {
          if (a >= q) {                     // uniform; dead a-groups skipped
            float4 ra = *(const float4*)&Pc[(ti + 16 * a) * PST + kk];
            ra.x *= iv4.x; ra.y *= iv4.y; ra.z *= iv4.z; ra.w *= iv4.w;
#pragma unroll
            for (int c = 0; c < 4; ++c) {
              if (32 * c + 31 >= b16q) {
                float v = acc[a][c];
                v = fmaf(-ra.x, rc4[c].x, v);
                v = fmaf(-ra.y, rc4[c].y, v);
                v = fmaf(-ra.z, rc4[c].z, v);
                v = fmaf(-ra.w, rc4[c].w, v);
                acc[a][c] = v;
              }
            }
          }
        }
      }
      // export next panel (cols 16q..16q+15): threads with tj-half == q&1, c-group q>>1
      if ((tj >> 4) == (q & 1)) {
        const int cq = q >> 1;
#pragma unroll
        for (int a = 0; a < 8; ++a) {
          if (a >= q) {
            const float v = (cq == 0) ? acc[a][0]
                          : (cq == 1) ? acc[a][1]
                          : (cq == 2) ? acc[a][2] : acc[a][3];
            Pn[(ti + 16 * a) * PST + (tj & 15)] = v;
          }
        }
      }
    }
  }

  // ---- final reduction (thread 0 == lane 0 of wave 0, holds ld/yb) ----
  if (t == 0) {
    const float alpha = 2.0625f;          // (1/NUG_MULT^2)+2
    const float alphaPost = alpha + 64.0f;
    const float beta = 1.0625f * nug;     // nug*(alpha-1)
    const float betaPost = beta + 0.5f * yb;
    const float loglik = -ld + alpha * __logf(beta) - alphaPost * __logf(betaPost)
                       + lgammaf(alphaPost) - lgammaf(alpha);
    atomicAdd(out, -loglik);
  }
}

// ---------------- host launch ----------------
extern "C" void kernel_launch(void* const* d_in, const int* in_sizes, int n_in,
                              void* d_out, int out_size, void* d_ws, size_t ws_size,
                              hipStream_t stream) {
  const float* Y = (const float*)d_in[0];
  const float* X = (const float*)d_in[1];
  const float* theta = (const float*)d_in[2];
  const int* NNmax = (const int*)d_in[3];
  const int* mPtr = (const int*)d_in[4];
  float* out = (float*)d_out;
  const int mMax = in_sizes[3] / N_COLS;  // 64

  hipMemsetAsync(out, 0, sizeof(float) * out_size, stream);
  chol_main<<<N_COLS, 512, 0, stream>>>(Y, X, theta, NNmax, mPtr, mMax, out);
}

// Round 6
// 755.189 us; speedup vs baseline: 2.1339x; 1.4017x over previous
//
#include <hip/hip_runtime.h>
#include <math.h>

#define N_COLS 2048   // N
#define N_ROWS 128    // n
#define KW     32     // W columns (m=30 + p=2)
#define WST    36     // LDS row stride for W (floats)
#define PST    20     // LDS row stride for panel (floats; 16B-aligned rows)

// ---------------- panel factorization: one wave, registers + __shfl broadcast ----------------
// Panel = 16 cols (global 16p..16p+15) x 128 rows in P (row stride PST), y implicit col.
// LDL raw columns: step k: inv=1/P[k][k]; for j>k: P[i][j] -= P[i][k]*inv*P[k][j] (i>k).
// Lane l owns rows l and l+64. p is RUNTIME (uniform); k/j loops compile-time.
static __device__ __forceinline__ void factor_panel(
    const int p, const int l, float* __restrict__ P, float* __restrict__ yL,
    float* __restrict__ invd, float& ld, float& yb) {
  float pr0[16], pr1[16];
#pragma unroll
  for (int qd = 0; qd < 4; ++qd) {
    const float4 v0 = *(const float4*)&P[l * PST + 4 * qd];
    const float4 v1 = *(const float4*)&P[(l + 64) * PST + 4 * qd];
    pr0[4 * qd + 0] = v0.x; pr0[4 * qd + 1] = v0.y; pr0[4 * qd + 2] = v0.z; pr0[4 * qd + 3] = v0.w;
    pr1[4 * qd + 0] = v1.x; pr1[4 * qd + 1] = v1.y; pr1[4 * qd + 2] = v1.z; pr1[4 * qd + 3] = v1.w;
  }
  float py0 = yL[l], py1 = yL[l + 64];
  const int pbase = p << 4;
#pragma unroll
  for (int k = 0; k < 16; ++k) {
    const int prow = pbase + k;      // runtime uniform
    const int olane = prow & 63;
    const bool hi = prow >= 64;      // runtime uniform -> cndmask select
    const float dk = __shfl(hi ? pr1[k] : pr0[k], olane, 64);
    const float yk = __shfl(hi ? py1 : py0, olane, 64);
    const float inv = __builtin_amdgcn_rcpf(dk);
    if (l == 0) { ld += 0.5f * __logf(dk); yb += yk * yk * inv; invd[k] = inv; }
    const float f0 = (l > prow) ? pr0[k] * inv : 0.0f;
    const float f1 = (l + 64 > prow) ? pr1[k] * inv : 0.0f;
#pragma unroll
    for (int j = k + 1; j < 16; ++j) {
      const float rk = __shfl(hi ? pr1[j] : pr0[j], olane, 64);
      pr0[j] = fmaf(-f0, rk, pr0[j]);
      pr1[j] = fmaf(-f1, rk, pr1[j]);
    }
    py0 = fmaf(-f0, yk, py0);
    py1 = fmaf(-f1, yk, py1);
  }
#pragma unroll
  for (int qd = 0; qd < 4; ++qd) {
    *(float4*)&P[l * PST + 4 * qd] =
        make_float4(pr0[4 * qd + 0], pr0[4 * qd + 1], pr0[4 * qd + 2], pr0[4 * qd + 3]);
    *(float4*)&P[(l + 64) * PST + 4 * qd] =
        make_float4(pr1[4 * qd + 0], pr1[4 * qd + 1], pr1[4 * qd + 2], pr1[4 * qd + 3]);
  }
  yL[l] = py0;
  yL[l + 64] = py1;
}

// ---------------- main kernel: one block (512 threads) per b ----------------
// Thread (ti,tj), ti=t&15, tj=t>>4 (0..31) owns G[ti+16a][tj+32c], a<8, c<4 -> acc[8][4].
// NOTE: single-arg launch_bounds. Empirically (rounds 1-5) the 2-arg form caps
// VGPRs at 512/(2*arg) on this toolchain and forced catastrophic scratch spill.
__global__ __launch_bounds__(512) void chol_main(
    const float* __restrict__ Y, const float* __restrict__ X,
    const float* __restrict__ theta, const int* __restrict__ NNmax,
    const int* __restrict__ mPtr, const int mMax, float* __restrict__ out) {
  // union: Wl (128x36 = 4608 f) overlaps the two panel buffers (2x 128x20 = 5120 f)
  __shared__ __align__(16) float uMem[5120];
  __shared__ float yL[N_ROWS];
  __shared__ float swL[N_ROWS];
  __shared__ __align__(16) float invd[16];
  __shared__ float smaskL[KW];
  __shared__ int nnL[KW];
  __shared__ int nzflag;
  float* const Wl = uMem;
  float* const P0 = uMem;
  float* const P1 = uMem + 2560;

  const int b = blockIdx.x;
  const int t = threadIdx.x;
  const int ti = t & 15;
  const int tj = t >> 4;   // 0..31

  // ---- per-block scalars (redundant per thread) ----
  const float th0 = theta[0], th1 = theta[1], th2 = theta[2], th3 = theta[3], th4 = theta[4];
  const float th5 = theta[5], th6 = theta[6], th7 = theta[7], th8 = theta[8], th9 = theta[9];
  const float logs = -__logf((float)(b + 1));
  const float nug = fmaxf(__expf(th0 + th1 * logs) - 1e-5f, 0.0f) + 1e-5f;
  const float sigma = __expf(th3 + th4 * logs);
  const float sig2 = sigma * sigma;
  const float invNug = 1.0f / nug;
  const float invL2 = __expf(-2.0f * th5) * (1.0f / 3.0f);
  const float sx0 = __expf(th6 + th8 * logs);
  const float sx1 = __expf(th7 + th9 * logs);
  int m = *mPtr; if (m > 30) m = 30;

  if (t == 0) nzflag = 0;
  if (t < KW) {
    nnL[t] = (t < m) ? NNmax[b * mMax + t] : 0;
    smaskL[t] = (t < m && t < b) ? __expf(0.5f * (float)(t + 1) * th2) : 0.0f;
  }
  __syncthreads();

  // ---- fill W (128 x 32) in LDS: each thread fills 8 cols of one row ----
  {
    const int i0 = t & 127;
    const int jb = t >> 7;   // 0..3
#pragma unroll
    for (int qq = 0; qq < 8; ++qq) {
      const int j = jb + 4 * qq;
      float v;
      if (j < m) {
        v = Y[i0 * N_COLS + nnL[j]] * smaskL[j];
      } else if (j < m + 2) {
        const int kc = j - m;
        v = X[(i0 * N_COLS + b) * 2 + kc] * ((kc == 0) ? sx0 : sx1);
      } else {
        v = 0.0f;
      }
      Wl[i0 * WST + j] = v;
    }
  }
  if (t < N_ROWS) {
    const float2 xv = ((const float2*)X)[t * N_COLS + b];
    if (xv.x != 0.0f || xv.y != 0.0f) atomicOr(&nzflag, 1);
    yL[t] = Y[t * N_COLS + b];
  }
  __syncthreads();
  if (nzflag == 0 && t < N_ROWS) {  // xz: zero the X part of W
    Wl[t * WST + m] = 0.0f;
    Wl[t * WST + m + 1] = 0.0f;
  }
  __syncthreads();

  // ---- Gram: acc[a][c] = W[i,:].W[j,:], i=ti+16a, j=tj+32c ----
  float acc[8][4];
#pragma unroll
  for (int a = 0; a < 8; ++a)
#pragma unroll
    for (int c = 0; c < 4; ++c) acc[a][c] = 0.0f;

#pragma unroll
  for (int kk = 0; kk < KW; kk += 4) {
    float4 wc[4];
#pragma unroll
    for (int c = 0; c < 4; ++c)
      wc[c] = *(const float4*)&Wl[(tj + 32 * c) * WST + kk];
#pragma unroll
    for (int a = 0; a < 8; ++a) {
      const float4 wa = *(const float4*)&Wl[(ti + 16 * a) * WST + kk];
#pragma unroll
      for (int c = 0; c < 4; ++c) {
        float v = acc[a][c];
        v = fmaf(wa.x, wc[c].x, v);
        v = fmaf(wa.y, wc[c].y, v);
        v = fmaf(wa.z, wc[c].z, v);
        v = fmaf(wa.w, wc[c].w, v);
        acc[a][c] = v;
      }
    }
  }

  // diag (row sum-of-squares) to swL: i==j needs ti==(tj&15); a = 2c + (tj>>4)
  if (ti == (tj & 15)) {
    if (tj < 16) {
#pragma unroll
      for (int c = 0; c < 4; ++c) swL[tj + 32 * c] = acc[2 * c][c];
    } else {
#pragma unroll
      for (int c = 0; c < 4; ++c) swL[tj + 32 * c] = acc[2 * c + 1][c];
    }
  }
  __syncthreads();

  // ---- transform dot -> G = I + (dot + matern*sig2)/nug ----
  if (b != 0) {
    float swa[8], swc[4];
#pragma unroll
    for (int a = 0; a < 8; ++a) swa[a] = swL[ti + 16 * a];
#pragma unroll
    for (int c = 0; c < 4; ++c) swc[c] = swL[tj + 32 * c];
#pragma unroll
    for (int a = 0; a < 8; ++a)
#pragma unroll
      for (int c = 0; c < 4; ++c) {
        const float d = acc[a][c];
        float r2 = (swa[a] + swc[c] - 2.0f * d) * invL2;
        r2 = fmaxf(r2, 0.0f);
        const float cc = sqrtf(3.0f * r2);
        const float mat = (1.0f + cc) * __expf(-cc);
        float g = fmaf(mat, sig2, d) * invNug;
        if (ti + 16 * a == tj + 32 * c) g += 1.0f;
        acc[a][c] = g;
      }
  } else {
#pragma unroll
    for (int a = 0; a < 8; ++a)
#pragma unroll
      for (int c = 0; c < 4; ++c)
        acc[a][c] = (ti + 16 * a == tj + 32 * c) ? 1.0f : 0.0f;
  }

  // export panel 0 (cols 0..15, all 128 rows): owned by threads tj<16, c=0
  if (tj < 16) {
#pragma unroll
    for (int a = 0; a < 8; ++a) P0[(ti + 16 * a) * PST + tj] = acc[a][0];
  }

  // ---- 8 panels (runtime loop): factor (wave 0) + rank-16 trailing update ----
  float ld = 0.0f, yb = 0.0f;
  for (int p = 0; p < 8; ++p) {
    float* const Pc = (p & 1) ? P1 : P0;
    float* const Pn = (p & 1) ? P0 : P1;
    __syncthreads();                       // panel p columns complete in Pc
    if (t < 64) factor_panel(p, t, Pc, yL, invd, ld, yb);
    __syncthreads();                       // factored panel + invd + yL visible
    const int q = p + 1;
    if (q < 8) {
      const int b16q = 16 * q;
#pragma unroll
      for (int kk = 0; kk < 16; kk += 4) {
        const float4 iv4 = *(const float4*)&invd[kk];
        float4 rc4[4];
#pragma unroll
        for (int c = 0; c < 4; ++c)
          if (32 * c + 31 >= b16q)          // uniform; dead c-groups skipped
            rc4[c] = *(const float4*)&Pc[(tj + 32 * c) * PST + kk];
#pragma unroll
        for (int a = 0; a < 8; ++a) {
          if (a >= q) {                     // uniform; dead a-groups skipped
            float4 ra = *(const float4*)&Pc[(ti + 16 * a) * PST + kk];
            ra.x *= iv4.x; ra.y *= iv4.y; ra.z *= iv4.z; ra.w *= iv4.w;
#pragma unroll
            for (int c = 0; c < 4; ++c) {
              if (32 * c + 31 >= b16q) {
                float v = acc[a][c];
                v = fmaf(-ra.x, rc4[c].x, v);
                v = fmaf(-ra.y, rc4[c].y, v);
                v = fmaf(-ra.z, rc4[c].z, v);
                v = fmaf(-ra.w, rc4[c].w, v);
                acc[a][c] = v;
              }
            }
          }
        }
      }
      // export next panel (cols 16q..16q+15): threads with tj-half == q&1, c-group q>>1
      if ((tj >> 4) == (q & 1)) {
        const int cq = q >> 1;
#pragma unroll
        for (int a = 0; a < 8; ++a) {
          if (a >= q) {
            const float v = (cq == 0) ? acc[a][0]
                          : (cq == 1) ? acc[a][1]
                          : (cq == 2) ? acc[a][2] : acc[a][3];
            Pn[(ti + 16 * a) * PST + (tj & 15)] = v;
          }
        }
      }
    }
  }

  // ---- final reduction (thread 0 == lane 0 of wave 0, holds ld/yb) ----
  if (t == 0) {
    const float alpha = 2.0625f;          // (1/NUG_MULT^2)+2
    const float alphaPost = alpha + 64.0f;
    const float beta = 1.0625f * nug;     // nug*(alpha-1)
    const float betaPost = beta + 0.5f * yb;
    const float loglik = -ld + alpha * __logf(beta) - alphaPost * __logf(betaPost)
                       + lgammaf(alphaPost) - lgammaf(alpha);
    atomicAdd(out, -loglik);
  }
}

// ---------------- host launch ----------------
extern "C" void kernel_launch(void* const* d_in, const int* in_sizes, int n_in,
                              void* d_out, int out_size, void* d_ws, size_t ws_size,
                              hipStream_t stream) {
  const float* Y = (const float*)d_in[0];
  const float* X = (const float*)d_in[1];
  const float* theta = (const float*)d_in[2];
  const int* NNmax = (const int*)d_in[3];
  const int* mPtr = (const int*)d_in[4];
  float* out = (float*)d_out;
  const int mMax = in_sizes[3] / N_COLS;  // 64

  hipMemsetAsync(out, 0, sizeof(float) * out_size, stream);
  chol_main<<<N_COLS, 512, 0, stream>>>(Y, X, theta, NNmax, mPtr, mMax, out);
}

// Round 7
// 400.866 us; speedup vs baseline: 4.0201x; 1.8839x over previous
//
#include <hip/hip_runtime.h>
#include <math.h>

#define N_COLS 2048   // N
#define N_ROWS 128    // n
#define KW     32     // W columns (m=30 + p=2)
#define WST    36     // LDS row stride for W (floats)
#define PST    20     // LDS row stride for panel (floats; 16B-aligned rows)

// ---------------- panel factorization: one wave, registers + __shfl broadcast ----------------
// Panel = 16 cols (global 16p..16p+15) x 128 rows in P (row stride PST), y implicit col.
// LDL raw columns: step k: inv=1/P[k][k]; for j>k: P[i][j] -= P[i][k]*inv*P[k][j] (i>k).
// Lane l owns rows l and l+64. p is RUNTIME (uniform); k/j loops compile-time.
static __device__ __forceinline__ void factor_panel(
    const int p, const int l, float* __restrict__ P, float* __restrict__ yL,
    float* __restrict__ invd, float& ld, float& yb) {
  float pr0[16], pr1[16];
#pragma unroll
  for (int qd = 0; qd < 4; ++qd) {
    const float4 v0 = *(const float4*)&P[l * PST + 4 * qd];
    const float4 v1 = *(const float4*)&P[(l + 64) * PST + 4 * qd];
    pr0[4 * qd + 0] = v0.x; pr0[4 * qd + 1] = v0.y; pr0[4 * qd + 2] = v0.z; pr0[4 * qd + 3] = v0.w;
    pr1[4 * qd + 0] = v1.x; pr1[4 * qd + 1] = v1.y; pr1[4 * qd + 2] = v1.z; pr1[4 * qd + 3] = v1.w;
  }
  float py0 = yL[l], py1 = yL[l + 64];
  const int pbase = p << 4;
#pragma unroll
  for (int k = 0; k < 16; ++k) {
    const int prow = pbase + k;      // runtime uniform
    const int olane = prow & 63;
    const bool hi = prow >= 64;      // runtime uniform -> cndmask select
    const float dk = __shfl(hi ? pr1[k] : pr0[k], olane, 64);
    const float yk = __shfl(hi ? py1 : py0, olane, 64);
    const float inv = __builtin_amdgcn_rcpf(dk);
    if (l == 0) { ld += 0.5f * __logf(dk); yb += yk * yk * inv; invd[k] = inv; }
    const float f0 = (l > prow) ? pr0[k] * inv : 0.0f;
    const float f1 = (l + 64 > prow) ? pr1[k] * inv : 0.0f;
#pragma unroll
    for (int j = k + 1; j < 16; ++j) {
      const float rk = __shfl(hi ? pr1[j] : pr0[j], olane, 64);
      pr0[j] = fmaf(-f0, rk, pr0[j]);
      pr1[j] = fmaf(-f1, rk, pr1[j]);
    }
    py0 = fmaf(-f0, yk, py0);
    py1 = fmaf(-f1, yk, py1);
  }
#pragma unroll
  for (int qd = 0; qd < 4; ++qd) {
    *(float4*)&P[l * PST + 4 * qd] =
        make_float4(pr0[4 * qd + 0], pr0[4 * qd + 1], pr0[4 * qd + 2], pr0[4 * qd + 3]);
    *(float4*)&P[(l + 64) * PST + 4 * qd] =
        make_float4(pr1[4 * qd + 0], pr1[4 * qd + 1], pr1[4 * qd + 2], pr1[4 * qd + 3]);
  }
  yL[l] = py0;
  yL[l + 64] = py1;
}

// ---------------- main kernel: one block (512 threads) per b ----------------
// Thread (ti,tj), ti=t&15, tj=t>>4 (0..31) owns G[ti+16a][tj+32c], a<8, c<4 -> acc[8][4].
// Single-arg launch_bounds: 2-arg form empirically caps VGPR at 512/(2*arg) on
// this toolchain (rounds 1-6) and forces scratch spill.
__global__ __launch_bounds__(512) void chol_main(
    const float* __restrict__ Y, const float* __restrict__ X,
    const float* __restrict__ theta, const int* __restrict__ NNmax,
    const int* __restrict__ mPtr, const int mMax, float* __restrict__ out) {
  // union: Wl (128x36 = 4608 f) overlaps the two panel buffers (2x 128x20 = 5120 f)
  __shared__ __align__(16) float uMem[5120];
  __shared__ float yL[N_ROWS];
  __shared__ float swL[N_ROWS];
  __shared__ __align__(16) float invd[16];
  __shared__ float smaskL[KW];
  __shared__ int nnL[KW];
  __shared__ int nzflag;
  float* const Wl = uMem;
  float* const P0 = uMem;
  float* const P1 = uMem + 2560;

  const int b = blockIdx.x;
  const int t = threadIdx.x;
  const int ti = t & 15;
  const int tj = t >> 4;   // 0..31

  // ---- per-block scalars (redundant per thread) ----
  const float th2 = theta[2];
  const float logs = -__logf((float)(b + 1));
  const float nug = fmaxf(__expf(theta[0] + theta[1] * logs) - 1e-5f, 0.0f) + 1e-5f;
  const float sigma = __expf(theta[3] + theta[4] * logs);
  const float sig2 = sigma * sigma;
  const float invNug = 1.0f / nug;
  const float invL2 = __expf(-2.0f * theta[5]) * (1.0f / 3.0f);
  const float sx0 = __expf(theta[6] + theta[8] * logs);
  const float sx1 = __expf(theta[7] + theta[9] * logs);
  int m = *mPtr; if (m > 30) m = 30;

  if (t == 0) nzflag = 0;
  if (t < KW) {
    nnL[t] = (t < m) ? NNmax[b * mMax + t] : 0;
    smaskL[t] = (t < m && t < b) ? __expf(0.5f * (float)(t + 1) * th2) : 0.0f;
  }
  __syncthreads();

  // ---- fill W (128 x 32) in LDS: each thread fills 8 cols of one row ----
  {
    const int i0 = t & 127;
    const int jb = t >> 7;   // 0..3
#pragma unroll
    for (int qq = 0; qq < 8; ++qq) {
      const int j = jb + 4 * qq;
      float v;
      if (j < m) {
        v = Y[i0 * N_COLS + nnL[j]] * smaskL[j];
      } else if (j < m + 2) {
        const int kc = j - m;
        v = X[(i0 * N_COLS + b) * 2 + kc] * ((kc == 0) ? sx0 : sx1);
      } else {
        v = 0.0f;
      }
      Wl[i0 * WST + j] = v;
    }
  }
  if (t < N_ROWS) {
    const float2 xv = ((const float2*)X)[t * N_COLS + b];
    if (xv.x != 0.0f || xv.y != 0.0f) atomicOr(&nzflag, 1);
    yL[t] = Y[t * N_COLS + b];
  }
  __syncthreads();
  if (nzflag == 0 && t < N_ROWS) {  // xz: zero the X part of W
    Wl[t * WST + m] = 0.0f;
    Wl[t * WST + m + 1] = 0.0f;
  }
  __syncthreads();

  // ---- Gram: acc[a][c] = W[i,:].W[j,:], i=ti+16a, j=tj+32c ----
  float acc[8][4];
#pragma unroll
  for (int a = 0; a < 8; ++a)
#pragma unroll
    for (int c = 0; c < 4; ++c) acc[a][c] = 0.0f;

#pragma unroll 2
  for (int kk = 0; kk < KW; kk += 4) {
    float4 wc[4];
#pragma unroll
    for (int c = 0; c < 4; ++c)
      wc[c] = *(const float4*)&Wl[(tj + 32 * c) * WST + kk];
#pragma unroll
    for (int a = 0; a < 8; ++a) {
      const float4 wa = *(const float4*)&Wl[(ti + 16 * a) * WST + kk];
#pragma unroll
      for (int c = 0; c < 4; ++c) {
        float v = acc[a][c];
        v = fmaf(wa.x, wc[c].x, v);
        v = fmaf(wa.y, wc[c].y, v);
        v = fmaf(wa.z, wc[c].z, v);
        v = fmaf(wa.w, wc[c].w, v);
        acc[a][c] = v;
      }
    }
  }

  // diag (row sum-of-squares) to swL: i==j needs ti==(tj&15); a = 2c + (tj>>4)
  if (ti == (tj & 15)) {
    if (tj < 16) {
#pragma unroll
      for (int c = 0; c < 4; ++c) swL[tj + 32 * c] = acc[2 * c][c];
    } else {
#pragma unroll
      for (int c = 0; c < 4; ++c) swL[tj + 32 * c] = acc[2 * c + 1][c];
    }
  }
  __syncthreads();

  // ---- transform dot -> G = I + (dot + matern*sig2)/nug ----
  // a-loop NOT unrolled: caps concurrent transcendental chains at 4.
  if (b != 0) {
    float swc[4];
#pragma unroll
    for (int c = 0; c < 4; ++c) swc[c] = swL[tj + 32 * c];
#pragma unroll 1
    for (int a = 0; a < 8; ++a) {
      const float swa = swL[ti + 16 * a];
#pragma unroll
      for (int c = 0; c < 4; ++c) {
        const float d = acc[a][c];
        float r2 = (swa + swc[c] - 2.0f * d) * invL2;
        r2 = fmaxf(r2, 0.0f);
        const float cc = sqrtf(3.0f * r2);
        const float mat = (1.0f + cc) * __expf(-cc);
        float g = fmaf(mat, sig2, d) * invNug;
        if (ti + 16 * a == tj + 32 * c) g += 1.0f;
        acc[a][c] = g;
      }
    }
  } else {
#pragma unroll
    for (int a = 0; a < 8; ++a)
#pragma unroll
      for (int c = 0; c < 4; ++c)
        acc[a][c] = (ti + 16 * a == tj + 32 * c) ? 1.0f : 0.0f;
  }

  // export panel 0 (cols 0..15, all 128 rows): owned by threads tj<16, c=0
  if (tj < 16) {
#pragma unroll
    for (int a = 0; a < 8; ++a) P0[(ti + 16 * a) * PST + tj] = acc[a][0];
  }

  // ---- 8 panels (runtime loop): factor (wave 0) + rank-16 trailing update ----
  float ld = 0.0f, yb = 0.0f;
  for (int p = 0; p < 8; ++p) {
    float* const Pc = (p & 1) ? P1 : P0;
    float* const Pn = (p & 1) ? P0 : P1;
    __syncthreads();                       // panel p columns complete in Pc
    if (t < 64) {
      // Explicit spill of acc[4..8) into Pn (dead: holds consumed panel p-1;
      // next write to Pn is the export AFTER the mid barrier). Frees 16 VGPRs
      // so factor_panel's 32-row working set fits under the 128 cap.
#pragma unroll
      for (int a = 4; a < 8; ++a)
        *(float4*)&Pn[t * 40 + 4 * (a - 4)] =
            make_float4(acc[a][0], acc[a][1], acc[a][2], acc[a][3]);
      factor_panel(p, t, Pc, yL, invd, ld, yb);
#pragma unroll
      for (int a = 4; a < 8; ++a) {
        const float4 v = *(const float4*)&Pn[t * 40 + 4 * (a - 4)];
        acc[a][0] = v.x; acc[a][1] = v.y; acc[a][2] = v.z; acc[a][3] = v.w;
      }
    }
    __syncthreads();                       // factored panel + invd + yL visible
    const int q = p + 1;
    if (q < 8) {
      const int b16q = 16 * q;
      // kk-loop NOT unrolled: pins live set to acc(32)+rc4(16)+ra(4)+iv4(4).
#pragma unroll 1
      for (int kk = 0; kk < 16; kk += 4) {
        const float4 iv4 = *(const float4*)&invd[kk];
        float4 rc4[4];
#pragma unroll
        for (int c = 0; c < 4; ++c)
          if (32 * c + 31 >= b16q)          // uniform; dead c-groups skipped
            rc4[c] = *(const float4*)&Pc[(tj + 32 * c) * PST + kk];
#pragma unroll
        for (int a = 0; a < 8; ++a) {
          if (a >= q) {                     // uniform; dead a-groups skipped
            float4 ra = *(const float4*)&Pc[(ti + 16 * a) * PST + kk];
            ra.x *= iv4.x; ra.y *= iv4.y; ra.z *= iv4.z; ra.w *= iv4.w;
#pragma unroll
            for (int c = 0; c < 4; ++c) {
              if (32 * c + 31 >= b16q) {
                float v = acc[a][c];
                v = fmaf(-ra.x, rc4[c].x, v);
                v = fmaf(-ra.y, rc4[c].y, v);
                v = fmaf(-ra.z, rc4[c].z, v);
                v = fmaf(-ra.w, rc4[c].w, v);
                acc[a][c] = v;
              }
            }
          }
        }
      }
      // export next panel (cols 16q..16q+15): threads with tj-half == q&1, c-group q>>1
      if ((tj >> 4) == (q & 1)) {
        const int cq = q >> 1;
#pragma unroll
        for (int a = 0; a < 8; ++a) {
          if (a >= q) {
            const float v = (cq == 0) ? acc[a][0]
                          : (cq == 1) ? acc[a][1]
                          : (cq == 2) ? acc[a][2] : acc[a][3];
            Pn[(ti + 16 * a) * PST + (tj & 15)] = v;
          }
        }
      }
    }
  }

  // ---- final reduction (thread 0 == lane 0 of wave 0, holds ld/yb) ----
  if (t == 0) {
    const float alpha = 2.0625f;          // (1/NUG_MULT^2)+2
    const float alphaPost = alpha + 64.0f;
    const float beta = 1.0625f * nug;     // nug*(alpha-1)
    const float betaPost = beta + 0.5f * yb;
    const float loglik = -ld + alpha * __logf(beta) - alphaPost * __logf(betaPost)
                       + lgammaf(alphaPost) - lgammaf(alpha);
    atomicAdd(out, -loglik);
  }
}

// ---------------- host launch ----------------
extern "C" void kernel_launch(void* const* d_in, const int* in_sizes, int n_in,
                              void* d_out, int out_size, void* d_ws, size_t ws_size,
                              hipStream_t stream) {
  const float* Y = (const float*)d_in[0];
  const float* X = (const float*)d_in[1];
  const float* theta = (const float*)d_in[2];
  const int* NNmax = (const int*)d_in[3];
  const int* mPtr = (const int*)d_in[4];
  float* out = (float*)d_out;
  const int mMax = in_sizes[3] / N_COLS;  // 64

  hipMemsetAsync(out, 0, sizeof(float) * out_size, stream);
  chol_main<<<N_COLS, 512, 0, stream>>>(Y, X, theta, NNmax, mPtr, mMax, out);
}